// Round 3
// baseline (1993.733 us; speedup 1.0000x reference)
//
#include <hip/hip_runtime.h>
#include <stdint.h>
#include <stddef.h>

#define BATCH 4096
#define HID   1024
#define EMB   64
#define KDIM  1088
#define NSTEP 19
#define NOBS  8

#define TPB   512
#define NBLK  256
#define BUFH  16384  // halfs per LDS buffer: A 256x32 (8192) + B 256x32 (8192)

typedef _Float16 f16;
typedef _Float16 half8 __attribute__((ext_vector_type(8)));
typedef float    float4v __attribute__((ext_vector_type(4)));

__device__ __forceinline__ float sigm(float x) { return 1.f / (1.f + __expf(-x)); }
__device__ __forceinline__ float tanh_f(float x) { return 1.f - 2.f / (__expf(2.f * x) + 1.f); }

__device__ __forceinline__ void gload_lds16(const void* gp, void* lp) {
  __builtin_amdgcn_global_load_lds(
      (const __attribute__((address_space(1))) uint32_t*)gp,
      (__attribute__((address_space(3))) uint32_t*)lp, 16, 0, 0);
}

// ---------------------------------------------------------------------------
// Software grid barrier (sense-reversing, device scope). Safe because
// NBLK == #CUs and one block always fits one CU -> all blocks co-resident.
// ---------------------------------------------------------------------------
__device__ __forceinline__ void gbar(unsigned* cnt, unsigned* gen) {
  __syncthreads();
  if (threadIdx.x == 0) {
    __threadfence();
    unsigned g = __hip_atomic_load(gen, __ATOMIC_RELAXED, __HIP_MEMORY_SCOPE_AGENT);
    unsigned t = __hip_atomic_fetch_add(cnt, 1u, __ATOMIC_ACQ_REL, __HIP_MEMORY_SCOPE_AGENT);
    if (t == NBLK - 1) {
      __hip_atomic_store(cnt, 0u, __ATOMIC_RELAXED, __HIP_MEMORY_SCOPE_AGENT);
      __hip_atomic_fetch_add(gen, 1u, __ATOMIC_RELEASE, __HIP_MEMORY_SCOPE_AGENT);
    } else {
      while (__hip_atomic_load(gen, __ATOMIC_ACQUIRE, __HIP_MEMORY_SCOPE_AGENT) == g)
        __builtin_amdgcn_s_sleep(2);
    }
    __threadfence();
  }
  __syncthreads();
}

// ---------------------------------------------------------------------------
// Pack W_ih|W_hh -> fp16 Wc[4096][1088].
// Packed row p = 256T + 128cp + 64v + 16g + u  <->  orig gate-g row
// T*64 + cp*32 + v*16 + u.  A block's 256-col tile T holds all 4 gates for
// 64 h-cols -> in-register cell epilogue.
// ---------------------------------------------------------------------------
__global__ void pack_kernel(const float* __restrict__ W_ih, const float* __restrict__ b_ih,
                            const float* __restrict__ W_hh, const float* __restrict__ b_hh,
                            f16* __restrict__ Wc, float* __restrict__ bc) {
  int gid = blockIdx.x * blockDim.x + threadIdx.x;
  int p = gid / KDIM;
  int k = gid - p * KDIM;
  int T = p >> 8;
  int cp = (p >> 7) & 1;
  int v = (p >> 6) & 1;
  int g = (p >> 4) & 3;
  int u = p & 15;
  int orig = g * HID + T * 64 + cp * 32 + v * 16 + u;
  float val = (k < EMB) ? W_ih[orig * EMB + k] : W_hh[orig * HID + (k - EMB)];
  Wc[gid] = (f16)val;
  if (k == 0) bc[p] = b_ih[orig] + b_hh[orig];
}

// ---------------------------------------------------------------------------
// Stage A (X rows bm*256..+255) and B (Wc rows bn*256..+255), 32 halfs of K
// each, into one LDS buffer. XOR-swizzled 16B chunks; 4 gload_lds16/thread.
// ---------------------------------------------------------------------------
__device__ __forceinline__ void stage_tiles(const f16* __restrict__ X, const f16* __restrict__ Wc,
                                            f16* sbuf, int k0, int bm, int bn, int tid, int w) {
  char* base = (char*)sbuf;
  {
    int s = tid;
    int r = s >> 2, cl = (s & 3) ^ ((r >> 1) & 3);
    gload_lds16((const char*)(X + (size_t)(bm * 256 + r) * KDIM + k0) + cl * 16,
                base + (size_t)(w * 64) * 16);
  }
  {
    int s = tid + 512;
    int r = s >> 2, cl = (s & 3) ^ ((r >> 1) & 3);
    gload_lds16((const char*)(X + (size_t)(bm * 256 + r) * KDIM + k0) + cl * 16,
                base + (size_t)(512 + w * 64) * 16);
  }
  {
    int s = tid;
    int r = s >> 2, cl = (s & 3) ^ ((r >> 1) & 3);
    gload_lds16((const char*)(Wc + (size_t)(bn * 256 + r) * KDIM + k0) + cl * 16,
                base + 16384 + (size_t)(w * 64) * 16);
  }
  {
    int s = tid + 512;
    int r = s >> 2, cl = (s & 3) ^ ((r >> 1) & 3);
    gload_lds16((const char*)(Wc + (size_t)(bn * 256 + r) * KDIM + k0) + cl * 16,
                base + 16384 + (size_t)(512 + w * 64) * 16);
  }
}

__device__ __forceinline__ void compute_tile(const f16* sb, const int* a_off, const int* b_off,
                                             float4v acc[4][8]) {
  half8 af[4];
#pragma unroll
  for (int mi = 0; mi < 4; ++mi) af[mi] = *(const half8*)(sb + a_off[mi]);
  half8 bf[4];
#pragma unroll
  for (int ni = 0; ni < 4; ++ni) bf[ni] = *(const half8*)(sb + b_off[ni]);
#pragma unroll
  for (int mi = 0; mi < 4; ++mi)
#pragma unroll
    for (int ni = 0; ni < 4; ++ni)
      acc[mi][ni] = __builtin_amdgcn_mfma_f32_16x16x32_f16(af[mi], bf[ni], acc[mi][ni], 0, 0, 0);
#pragma unroll
  for (int ni = 0; ni < 4; ++ni) bf[ni] = *(const half8*)(sb + b_off[4 + ni]);
#pragma unroll
  for (int mi = 0; mi < 4; ++mi)
#pragma unroll
    for (int ni = 0; ni < 4; ++ni)
      acc[mi][ni + 4] = __builtin_amdgcn_mfma_f32_16x16x32_f16(af[mi], bf[ni], acc[mi][ni + 4], 0, 0, 0);
}

// out[row][0:5] = h[row] @ W_out^T + b_out for the block's 16 rows (2/wave).
__device__ __forceinline__ void do_outproj(const f16* __restrict__ Xh,
                                           const float* __restrict__ W_out,
                                           const float* __restrict__ b_out,
                                           float* __restrict__ out_t,
                                           float (*s_nv)[2], int L, int w, int lane) {
#pragma unroll
  for (int rr = 0; rr < 2; ++rr) {
    const int row = L * 16 + w * 2 + rr;
    const f16* hrow = Xh + (size_t)row * KDIM + EMB;
    half8 h0 = *(const half8*)(hrow + lane * 16);
    half8 h1 = *(const half8*)(hrow + lane * 16 + 8);
    float a[5];
#pragma unroll
    for (int o = 0; o < 5; ++o) {
      const float* wo = W_out + o * HID + lane * 16;
      float s = 0.f;
#pragma unroll
      for (int e = 0; e < 8; ++e) s += (float)h0[e] * wo[e];
#pragma unroll
      for (int e = 0; e < 8; ++e) s += (float)h1[e] * wo[8 + e];
      a[o] = s;
    }
#pragma unroll
    for (int sh = 32; sh > 0; sh >>= 1)
#pragma unroll
      for (int o = 0; o < 5; ++o) a[o] += __shfl_down(a[o], sh, 64);
    if (lane == 0) {
#pragma unroll
      for (int o = 0; o < 5; ++o) out_t[(size_t)row * 5 + o] = a[o] + b_out[o];
      s_nv[w * 2 + rr][0] = a[0] + b_out[0];
      s_nv[w * 2 + rr][1] = a[1] + b_out[1];
    }
  }
}

// emb for step t_next (obs phase) into X[:,0:64] for the block's 16 rows
__device__ __forceinline__ void write_emb_obs(const float* __restrict__ observed, int t_next,
                                              const float* __restrict__ W_emb,
                                              const float* __restrict__ b_emb,
                                              f16* __restrict__ Xn, int L, int tid) {
  for (int s = tid; s < 1024; s += TPB) {
    int rr = s >> 6, jc = s & 63;
    int row = L * 16 + rr;
    const float* o0 = observed + (size_t)t_next * BATCH * 2 + row * 2;
    const float* o1 = o0 + BATCH * 2;
    float d0 = o1[0] - o0[0], d1 = o1[1] - o0[1];
    float v = d0 * W_emb[2 * jc] + d1 * W_emb[2 * jc + 1] + b_emb[jc];
    Xn[(size_t)row * KDIM + jc] = (f16)fmaxf(v, 0.f);
  }
}

// ---------------------------------------------------------------------------
__global__ __launch_bounds__(TPB, 2)
void lstm_kernel(const float* __restrict__ observed,
                 const float* __restrict__ W_emb, const float* __restrict__ b_emb,
                 const f16* __restrict__ Wc, const float* __restrict__ bc,
                 const float* __restrict__ W_out, const float* __restrict__ b_out,
                 f16* __restrict__ X0, f16* __restrict__ X1,
                 float* __restrict__ out, unsigned* __restrict__ bar) {
  __shared__ f16 smem[2 * BUFH];
  __shared__ float s_nv[16][2];
  unsigned* cnt = bar;
  unsigned* gen = bar + 1;

  const int tid = threadIdx.x;
  const int lane = tid & 63;
  const int w = tid >> 6;
  const int l15 = lane & 15;
  const int quad = lane >> 4;
  const int L = blockIdx.x;
  const int bn = L & 15;   // same-bn blocks share an XCD -> Wc strip L2-pinned
  const int bm = L >> 4;
  const int rowPanel = w & 3;    // 4 x 64 rows
  const int colPanel = w >> 2;   // 2 x 128 packed cols

  // loop-invariant LDS fragment offsets (halfs)
  int a_off[4], b_off[8];
#pragma unroll
  for (int mi = 0; mi < 4; ++mi) {
    int ra = rowPanel * 64 + mi * 16 + l15;
    a_off[mi] = ra * 32 + (quad ^ ((ra >> 1) & 3)) * 8;
  }
#pragma unroll
  for (int ni = 0; ni < 8; ++ni) {
    int rb = colPanel * 128 + ni * 16 + l15;
    b_off[ni] = 8192 + rb * 32 + (quad ^ ((rb >> 1) & 3)) * 8;
  }

  // bias (4 gates x 2 vee-groups) and h-col base, constant across steps
  float bq[2][4];
#pragma unroll
  for (int v = 0; v < 2; ++v)
#pragma unroll
    for (int g = 0; g < 4; ++g)
      bq[v][g] = bc[bn * 256 + colPanel * 128 + v * 64 + g * 16 + l15];

  float c_reg[32];
#pragma unroll
  for (int i = 0; i < 32; ++i) c_reg[i] = 0.f;

  // prologue: emb(0) into X0
  write_emb_obs(observed, 0, W_emb, b_emb, X0, L, tid);
  gbar(cnt, gen);

  for (int t = 0; t < NSTEP; ++t) {
    const f16* Xc = (t & 1) ? X1 : X0;
    f16* Xn = (t & 1) ? X0 : X1;

    float4v acc[4][8];
#pragma unroll
    for (int mi = 0; mi < 4; ++mi)
#pragma unroll
      for (int ni = 0; ni < 8; ++ni) acc[mi][ni] = (float4v){0.f, 0.f, 0.f, 0.f};

    stage_tiles(Xc, Wc, smem, 0, bm, bn, tid, w);

    // deferred out-projection for obs steps (h(t-1) lives in Xc)
    if (t >= 1 && t <= 7)
      do_outproj(Xc, W_out, b_out, out + (size_t)(t - 1) * BATCH * 5, s_nv, L, w, lane);

    for (int kt = 0; kt < 34; kt += 2) {
      __syncthreads();
      if (kt + 1 < 34) stage_tiles(Xc, Wc, smem + BUFH, (kt + 1) * 32, bm, bn, tid, w);
      compute_tile(smem, a_off, b_off, acc);
      __syncthreads();
      if (kt + 2 < 34) stage_tiles(Xc, Wc, smem, (kt + 2) * 32, bm, bn, tid, w);
      compute_tile(smem + BUFH, a_off, b_off, acc);
    }

    // in-register LSTM cell epilogue
#pragma unroll
    for (int mi = 0; mi < 4; ++mi) {
#pragma unroll
      for (int v = 0; v < 2; ++v) {
        const int jj = bn * 64 + colPanel * 32 + v * 16 + l15;
#pragma unroll
        for (int r = 0; r < 4; ++r) {
          const int row = bm * 256 + rowPanel * 64 + mi * 16 + quad * 4 + r;
          float gi = acc[mi][v * 4 + 0][r] + bq[v][0];
          float gf = acc[mi][v * 4 + 1][r] + bq[v][1];
          float gg = acc[mi][v * 4 + 2][r] + bq[v][2];
          float go = acc[mi][v * 4 + 3][r] + bq[v][3];
          float cn = sigm(gf) * c_reg[(mi * 2 + v) * 4 + r] + sigm(gi) * tanh_f(gg);
          c_reg[(mi * 2 + v) * 4 + r] = cn;
          float h = sigm(go) * tanh_f(cn);
          Xn[(size_t)row * KDIM + EMB + jj] = (f16)h;
        }
      }
    }

    if (t + 1 < NOBS) write_emb_obs(observed, t + 1, W_emb, b_emb, Xn, L, tid);

    gbar(cnt, gen);

    if (t >= 7) {
      do_outproj(Xn, W_out, b_out, out + (size_t)t * BATCH * 5, s_nv, L, w, lane);
      if (t + 1 < NSTEP) {
        __syncthreads();  // s_nv visibility within block
        for (int s = tid; s < 1024; s += TPB) {
          int rr = s >> 6, jc = s & 63;
          int row = L * 16 + rr;
          float d0 = s_nv[rr][0], d1 = s_nv[rr][1];
          float v = d0 * W_emb[2 * jc] + d1 * W_emb[2 * jc + 1] + b_emb[jc];
          Xn[(size_t)row * KDIM + jc] = (f16)fmaxf(v, 0.f);
        }
        gbar(cnt, gen);
      }
    }
  }
}

// ---------------------------------------------------------------------------
extern "C" void kernel_launch(void* const* d_in, const int* in_sizes, int n_in,
                              void* d_out, int out_size, void* d_ws, size_t ws_size,
                              hipStream_t stream) {
  const float* observed = (const float*)d_in[0];
  const float* W_emb = (const float*)d_in[1];
  const float* b_emb = (const float*)d_in[2];
  const float* W_ih = (const float*)d_in[3];
  const float* b_ih = (const float*)d_in[4];
  const float* W_hh = (const float*)d_in[5];
  const float* b_hh = (const float*)d_in[6];
  const float* W_out = (const float*)d_in[7];
  const float* b_out = (const float*)d_in[8];
  float* out = (float*)d_out;

  uint8_t* ws = (uint8_t*)d_ws;
  const size_t WC_BYTES = (size_t)4096 * KDIM * sizeof(f16);  // 8,912,896
  f16* Wc = (f16*)ws;
  float* bc = (float*)(ws + WC_BYTES);
  f16* X0 = (f16*)(ws + WC_BYTES + 16384);
  f16* X1 = (f16*)(ws + 2 * WC_BYTES + 16384);
  unsigned* bar = (unsigned*)(ws + 3 * WC_BYTES + 16384);

  pack_kernel<<<(4096 * KDIM) / 256, 256, 0, stream>>>(W_ih, b_ih, W_hh, b_hh, Wc, bc);
  hipMemsetAsync(X0, 0, WC_BYTES, stream);  // h0 = 0 (emb cols written in-kernel)
  hipMemsetAsync(bar, 0, 128, stream);      // barrier cnt/gen = 0

  lstm_kernel<<<NBLK, TPB, 0, stream>>>(observed, W_emb, b_emb, Wc, bc,
                                        W_out, b_out, X0, X1, out, bar);
}